// Round 3
// baseline (213.012 us; speedup 1.0000x reference)
//
#include <hip/hip_runtime.h>

// skipConnection: out[i] = in[i,0]*w + in[i,1]*(1-w)
// Memory-bound elementwise. 192 MiB mandatory traffic; fills in the same timed
// region run at 6.7-6.8 TB/s so ~29 us is the kernel floor. Timed total also
// contains ~159 us of harness re-poison fills (2x 512 MiB) -> no L3 reuse
// possible, hence nontemporal everywhere.
// Round-2 lesson: persistent grid-stride was -4 us vs flat. Revert to flat,
// widen to 8 outputs/thread (4x 16B nt loads + 2x 16B nt stores = 96 B/lane)
// for more loads-in-flight per lane and half the wave count.

typedef float v4f __attribute__((ext_vector_type(4)));

__global__ __launch_bounds__(256) void skipConnection_kernel(
    const v4f* __restrict__ in,   // [N/2] v4f = [N] (x,y) pairs packed 2-per-vec
    const float* __restrict__ wp, // device scalar weight
    v4f* __restrict__ out,        // [N/4] v4f outputs
    int n8)                       // N/8
{
    int i = blockIdx.x * blockDim.x + threadIdx.x;
    if (i >= n8) return;

    const float w  = wp[0];
    const float wm = 1.0f - w;

    // lane reads 64 contiguous bytes (pairs 8i..8i+7), writes 32 contiguous bytes.
    v4f a = __builtin_nontemporal_load(&in[4 * i]);     // (x0,y0,x1,y1)
    v4f b = __builtin_nontemporal_load(&in[4 * i + 1]); // (x2,y2,x3,y3)
    v4f c = __builtin_nontemporal_load(&in[4 * i + 2]); // (x4,y4,x5,y5)
    v4f d = __builtin_nontemporal_load(&in[4 * i + 3]); // (x6,y6,x7,y7)

    v4f o0, o1;
    o0.x = fmaf(a.x, w, a.y * wm);
    o0.y = fmaf(a.z, w, a.w * wm);
    o0.z = fmaf(b.x, w, b.y * wm);
    o0.w = fmaf(b.z, w, b.w * wm);
    o1.x = fmaf(c.x, w, c.y * wm);
    o1.y = fmaf(c.z, w, c.w * wm);
    o1.z = fmaf(d.x, w, d.y * wm);
    o1.w = fmaf(d.z, w, d.w * wm);

    __builtin_nontemporal_store(o0, &out[2 * i]);
    __builtin_nontemporal_store(o1, &out[2 * i + 1]);
}

extern "C" void kernel_launch(void* const* d_in, const int* in_sizes, int n_in,
                              void* d_out, int out_size, void* d_ws, size_t ws_size,
                              hipStream_t stream) {
    const float* in = (const float*)d_in[0];   // [N,2] fp32
    const float* wp = (const float*)d_in[1];   // [1,1] fp32
    float* out      = (float*)d_out;           // [N,1] fp32

    int n  = out_size;        // N = 16777216
    int n8 = n / 8;           // N divisible by 8
    int block = 256;
    int grid  = (n8 + block - 1) / block;  // 8192 blocks, flat one-shot

    skipConnection_kernel<<<grid, block, 0, stream>>>(
        (const v4f*)in, wp, (v4f*)out, n8);
}

// Round 4
// 198.820 us; speedup vs baseline: 1.0714x; 1.0714x over previous
//
#include <hip/hip_runtime.h>

// skipConnection: out[i] = in[i,0]*w + in[i,1]*(1-w)
// Memory-bound elementwise. 192 MiB mandatory HBM traffic.
// Timed region = ~157 us of harness re-poison fills (2x 512 MiB @ ~6.8 TB/s,
// untouchable, also thrash L3 so no cross-iteration reuse) + this kernel.
// Swept variants: nt/cacheable x flat/grid-stride x 4/8-wide. Best measured:
// nt + flat + 4 outputs/thread (200.1 us total, kernel ~43 us ~= 72% of the
// 6.29 TB/s mixed-stream copy ceiling). This is the revert to that optimum.
//  - grid-stride: +4 us (loop overhead, no TLP benefit at 524288 threads)
//  - cacheable:   +6 us (L3 allocation cost, zero reuse available)
//  - 8-wide:      +13 us (half the waves, serialized lane accesses)

typedef float v4f __attribute__((ext_vector_type(4)));  // native vector: legal for nontemporal builtins

__global__ __launch_bounds__(256) void skipConnection_kernel(
    const v4f* __restrict__ in,   // [N/2] v4f = [N] (x,y) pairs packed 2-per-vec
    const float* __restrict__ wp, // device scalar weight
    v4f* __restrict__ out,        // [N/4] v4f outputs
    int n4)                       // N/4
{
    int i = blockIdx.x * blockDim.x + threadIdx.x;
    if (i >= n4) return;

    const float w  = wp[0];
    const float wm = 1.0f - w;

    // lane reads 32 contiguous bytes: pairs (4i..4i+3). Streaming, zero reuse -> nt.
    v4f a = __builtin_nontemporal_load(&in[2 * i]);     // (x0,y0,x1,y1)
    v4f b = __builtin_nontemporal_load(&in[2 * i + 1]); // (x2,y2,x3,y3)

    v4f o;
    o.x = fmaf(a.x, w, a.y * wm);
    o.y = fmaf(a.z, w, a.w * wm);
    o.z = fmaf(b.x, w, b.y * wm);
    o.w = fmaf(b.z, w, b.w * wm);

    __builtin_nontemporal_store(o, &out[i]);
}

extern "C" void kernel_launch(void* const* d_in, const int* in_sizes, int n_in,
                              void* d_out, int out_size, void* d_ws, size_t ws_size,
                              hipStream_t stream) {
    const float* in = (const float*)d_in[0];   // [N,2] fp32
    const float* wp = (const float*)d_in[1];   // [1,1] fp32
    float* out      = (float*)d_out;           // [N,1] fp32

    int n  = out_size;        // N = 16777216
    int n4 = n / 4;           // N divisible by 4
    int block = 256;
    int grid  = (n4 + block - 1) / block;

    skipConnection_kernel<<<grid, block, 0, stream>>>(
        (const v4f*)in, wp, (v4f*)out, n4);
}